// Round 3
// baseline (587.938 us; speedup 1.0000x reference)
//
#include <hip/hip_runtime.h>
#include <cmath>

// ---- problem constants ----
#define BATCH 16
#define HEADS 16
#define SEQ   512
#define DIM   64

#define LAMBDA_A 0.33f
#define LAMBDA_D 0.33f
#define LAMBDA_J 0.34f    // 1 - 0.33 - 0.33
#define NEG_BIG  1.0e12f

typedef float  floatx4 __attribute__((ext_vector_type(4)));
typedef short  shortx8 __attribute__((ext_vector_type(8)));
typedef short  shortx4 __attribute__((ext_vector_type(4)));

__device__ __forceinline__ unsigned short f2bf(float x){
  unsigned u = __builtin_bit_cast(unsigned, x);
  u += 0x7FFFu + ((u >> 16) & 1u);          // round-to-nearest-even
  return (unsigned short)(u >> 16);
}

// ---------------------------------------------------------------------------
// fused prep:
//   blocks [0, 2048):    W[b,q,k] = LAMBDA_D*p_dist + LAMBDA_J*adj_norm
//   blocks [2048, 4096): K -> bf16 (B,H,S,D), V -> bf16 V^T (B,H,D,S)
// ---------------------------------------------------------------------------
__global__ __launch_bounds__(256, 8) void prep_kernel(
    const float* __restrict__ adj, const float* __restrict__ dist,
    const float* __restrict__ mask, const float* __restrict__ K,
    const float* __restrict__ V, float* __restrict__ W,
    unsigned short* __restrict__ Kb, unsigned short* __restrict__ VTb)
{
  __shared__ unsigned short sT[64 * 72];
  int tid = threadIdx.x;

  if (blockIdx.x < BATCH * SEQ / 4){
    // ---- W prep: one wave per (b,q) row ----
    int lane = tid & 63;
    int row  = blockIdx.x * 4 + (tid >> 6);     // 0 .. B*SEQ-1
    int b = row >> 9, q = row & (SEQ - 1);
    const float* arow = adj  + ((size_t)b * SEQ + q) * SEQ;
    const float* drow = dist + ((size_t)b * SEQ + q) * SEQ;
    const float* mrow = mask + (size_t)b * SEQ;

    floatx4 a[2], e[2];
    float asum = 0.f, dsum = 0.f;
#pragma unroll
    for (int i = 0; i < 2; i++){
      int c4 = (i * 64 + lane) * 4;
      a[i] = *(const floatx4*)(arow + c4);
      floatx4 d4 = *(const floatx4*)(drow + c4);
      floatx4 m4 = *(const floatx4*)(mrow + c4);
#pragma unroll
      for (int j = 0; j < 4; j++){
        asum += a[i][j];
        float ex = (m4[j] == 0.f) ? 0.f : __expf(-d4[j]);
        e[i][j] = ex;
        dsum += ex;
      }
    }
#pragma unroll
    for (int off = 1; off < 64; off <<= 1){
      asum += __shfl_xor(asum, off);
      dsum += __shfl_xor(dsum, off);
    }
    float ia = LAMBDA_J / (asum + 1e-6f);
    float id = LAMBDA_D / dsum;

    float* wrow = W + ((size_t)b * SEQ + q) * SEQ;
#pragma unroll
    for (int i = 0; i < 2; i++){
      int c4 = (i * 64 + lane) * 4;
      floatx4 w;
#pragma unroll
      for (int j = 0; j < 4; j++) w[j] = e[i][j] * id + a[i][j] * ia;
      *(floatx4*)(wrow + c4) = w;
    }
    return;
  }

  // ---- K/V prep: one block per (bh, 64-row chunk) ----
  int bid = blockIdx.x - BATCH * SEQ / 4;
  int c   = bid & 7;
  int bh  = bid >> 3;
  const float* Kp = K + ((size_t)bh * SEQ + c * 64) * DIM;
  const float* Vp = V + ((size_t)bh * SEQ + c * 64) * DIM;
  unsigned short* Ko = Kb  + ((size_t)bh * SEQ + c * 64) * DIM;
  unsigned short* Vo = VTb + (size_t)bh * DIM * SEQ;

#pragma unroll
  for (int i = 0; i < 2; i++){
    int idx = (i * 256 + tid) * 8;
    floatx4 v0 = *(const floatx4*)(Kp + idx);
    floatx4 v1 = *(const floatx4*)(Kp + idx + 4);
    shortx8 hh;
#pragma unroll
    for (int j = 0; j < 4; j++){
      hh[j]     = (short)f2bf(v0[j]);
      hh[j + 4] = (short)f2bf(v1[j]);
    }
    *(shortx8*)(Ko + idx) = hh;
  }

#pragma unroll
  for (int i = 0; i < 4; i++){
    int idx = (i * 256 + tid) * 4;
    int k = idx >> 6, d = idx & 63;
    floatx4 v = *(const floatx4*)(Vp + idx);
#pragma unroll
    for (int j = 0; j < 4; j++) sT[(d + j) * 72 + k] = f2bf(v[j]);
  }
  __syncthreads();
#pragma unroll
  for (int i = 0; i < 2; i++){
    int idx = i * 256 + tid;
    int d = idx >> 3, k8 = idx & 7;
    shortx8 hh = *(const shortx8*)&sT[d * 72 + k8 * 8];
    *(shortx8*)(Vo + (size_t)d * SEQ + c * 64 + k8 * 8) = hh;
  }
}

// ---------------------------------------------------------------------------
// main kernel, ZERO barriers, LOW register footprint:
//  - block = (b, h, 64 q-rows); each of 4 waves owns 16 q-rows x all 512 keys
//  - QK^T swapped (A=K, B=Q): score[key = j*16 + quad*4 + r][q = l15]
//  - pass A: online (m, l) over 32 key-tiles, scores DISCARDED (no acc[32] hog)
//  - pass B: recompute scores per 64-key chunk (MFMA is ~3% utilized -- free),
//            exp + p_attn float4 store + p_weighted slab + PV MFMA
//  - P~ -> PV A-fragment transpose via per-wave-private LDS slab (no barrier)
// ---------------------------------------------------------------------------
__global__ __launch_bounds__(256, 4) void attn_kernel(
    const float* __restrict__ Q, const unsigned short* __restrict__ Kb,
    const unsigned short* __restrict__ VTb, const float* __restrict__ mask,
    const float* __restrict__ W, float* __restrict__ out, float* __restrict__ pattn)
{
  int bx = blockIdx.x;
  int qt = bx & 7;
  int h  = (bx >> 3) & 15;
  int b  = bx >> 7;
  int bh = b * HEADS + h;

  int tid  = threadIdx.x;
  int wv   = tid >> 6;
  int lane = tid & 63;
  int l15  = lane & 15;
  int quad = lane >> 4;
  int q0   = qt * 64 + wv * 16;          // wave's first q row

  __shared__ short sPW[4][16 * 72];      // per-wave private slab
  short* slab = &sPW[wv][0];

  // ---- Q fragments (B operand), rows q = q0 + l15, prescaled by 1/8 ----
  const float* Qp = Q + ((size_t)bh * SEQ + q0 + l15) * DIM + quad * 8;
  shortx8 qf[2];
#pragma unroll
  for (int ks = 0; ks < 2; ks++){
    floatx4 v0 = *(const floatx4*)(Qp + ks * 32);
    floatx4 v1 = *(const floatx4*)(Qp + ks * 32 + 4);
#pragma unroll
    for (int j = 0; j < 4; j++){
      qf[ks][j]     = (short)f2bf(v0[j] * 0.125f);
      qf[ks][j + 4] = (short)f2bf(v1[j] * 0.125f);
    }
  }

  const unsigned short* Kw = Kb + (size_t)bh * SEQ * DIM
                                + (size_t)l15 * DIM + quad * 8;
  const float* mrow = mask + b * SEQ + quad * 4;

  // ---- pass A: online (m, l), scores discarded ----
  float mx = -INFINITY, lsum = 0.f;
#pragma unroll
  for (int j = 0; j < 32; j++){
    const unsigned short* Kt = Kw + (size_t)j * 16 * DIM;
    shortx8 k0 = *(const shortx8*)(Kt);
    shortx8 k1 = *(const shortx8*)(Kt + 32);
    floatx4 t = (floatx4)0.f;
    t = __builtin_amdgcn_mfma_f32_16x16x32_bf16(k0, qf[0], t, 0, 0, 0);
    t = __builtin_amdgcn_mfma_f32_16x16x32_bf16(k1, qf[1], t, 0, 0, 0);
    floatx4 m4 = *(const floatx4*)(mrow + j * 16);
    float s0 = (m4[0] == 0.f) ? -NEG_BIG : t[0];
    float s1 = (m4[1] == 0.f) ? -NEG_BIG : t[1];
    float s2 = (m4[2] == 0.f) ? -NEG_BIG : t[2];
    float s3 = (m4[3] == 0.f) ? -NEG_BIG : t[3];
    float tm = fmaxf(fmaxf(s0, s1), fmaxf(s2, s3));
    float mn = fmaxf(mx, tm);
    lsum = lsum * __expf(mx - mn)
         + __expf(s0 - mn) + __expf(s1 - mn)
         + __expf(s2 - mn) + __expf(s3 - mn);
    mx = mn;
  }
  // cross-quad combine of (m, l)
#pragma unroll
  for (int off = 16; off < 64; off <<= 1){
    float m2 = __shfl_xor(mx, off);
    float l2 = __shfl_xor(lsum, off);
    float mn = fmaxf(mx, m2);
    lsum = lsum * __expf(mx - mn) + l2 * __expf(m2 - mn);
    mx = mn;
  }
  float inv_l  = 1.f / lsum;
  float lam_il = LAMBDA_A * inv_l;

  // ---- pass B: recompute per chunk, build + PV, no barriers ----
  float* pAl = pattn + ((size_t)bh * SEQ + q0 + l15) * SEQ + quad * 4;
  const float* Wl = W + ((size_t)b * SEQ + q0 + l15) * SEQ + quad * 4;
  const unsigned short* Vw = VTb + (size_t)bh * DIM * SEQ
                                 + (size_t)l15 * SEQ + quad * 8;

  floatx4 acc2[4];
#pragma unroll
  for (int d = 0; d < 4; d++) acc2[d] = (floatx4)0.f;

#pragma unroll
  for (int cc = 0; cc < 8; cc++){
    // W for this chunk (issued first; latency hidden under the MFMAs below)
    floatx4 wc[4];
#pragma unroll
    for (int jj = 0; jj < 4; jj++)
      wc[jj] = *(const floatx4*)(Wl + cc * 64 + jj * 16);

    // recompute 4 score tiles, exp, p_attn store, p_weighted into slab
#pragma unroll
    for (int jj = 0; jj < 4; jj++){
      int j = cc * 4 + jj;
      const unsigned short* Kt = Kw + (size_t)j * 16 * DIM;
      shortx8 k0 = *(const shortx8*)(Kt);
      shortx8 k1 = *(const shortx8*)(Kt + 32);
      floatx4 t = (floatx4)0.f;
      t = __builtin_amdgcn_mfma_f32_16x16x32_bf16(k0, qf[0], t, 0, 0, 0);
      t = __builtin_amdgcn_mfma_f32_16x16x32_bf16(k1, qf[1], t, 0, 0, 0);
      floatx4 m4 = *(const floatx4*)(mrow + j * 16);
      floatx4 pa;
      shortx4 pw;
#pragma unroll
      for (int r = 0; r < 4; r++){
        float s = (m4[r] == 0.f) ? -NEG_BIG : t[r];
        float e = __expf(s - mx);
        pa[r] = e * inv_l;
        pw[r] = (short)f2bf(fmaf(e, lam_il, wc[jj][r]));
      }
      __builtin_nontemporal_store(pa, (floatx4*)(pAl + j * 16));
      *(shortx4*)&slab[l15 * 72 + jj * 16 + quad * 4] = pw;
    }

    // PV MFMA for this chunk (A from slab, B streams from V^T)
    const unsigned short* Vc = Vw + cc * 64;
#pragma unroll
    for (int ks = 0; ks < 2; ks++){
      shortx8 a2 = *(const shortx8*)&slab[l15 * 72 + ks * 32 + quad * 8];
#pragma unroll
      for (int d = 0; d < 4; d++){
        shortx8 vf = *(const shortx8*)(Vc + (size_t)d * 16 * SEQ + ks * 32);
        acc2[d] = __builtin_amdgcn_mfma_f32_16x16x32_bf16(a2, vf, acc2[d], 0, 0, 0);
      }
    }
  }

  // ---- epilogue: out (B,H,S,D); row q = q0 + quad*4 + r, col d*16 + l15 ----
  float* ob = out + ((size_t)bh * SEQ + q0 + quad * 4) * DIM + l15;
#pragma unroll
  for (int d = 0; d < 4; d++){
#pragma unroll
    for (int r = 0; r < 4; r++)
      __builtin_nontemporal_store(acc2[d][r], ob + (size_t)r * DIM + d * 16);
  }
}

extern "C" void kernel_launch(void* const* d_in, const int* in_sizes, int n_in,
                              void* d_out, int out_size, void* d_ws, size_t ws_size,
                              hipStream_t stream){
  const float* Q    = (const float*)d_in[0];
  const float* K    = (const float*)d_in[1];
  const float* V    = (const float*)d_in[2];
  const float* mask = (const float*)d_in[3];
  const float* adj  = (const float*)d_in[4];
  const float* dist = (const float*)d_in[5];
  float* out   = (float*)d_out;
  float* pattn = out + (size_t)BATCH * HEADS * SEQ * DIM;   // 8,388,608

  // workspace layout (48 MiB):
  //   [0,16M)   W     f32  (B,S,S)   head-independent weight term
  //   [16M,32M) Kb    bf16 (B,H,S,D)
  //   [32M,48M) VT    bf16 (B,H,D,S)
  float*          Wbuf = (float*)d_ws;
  unsigned short* Kb   = (unsigned short*)((char*)d_ws + (size_t)16 * 1024 * 1024);
  unsigned short* VTb  = (unsigned short*)((char*)d_ws + (size_t)32 * 1024 * 1024);

  prep_kernel<<<BATCH * SEQ / 4 + BATCH * HEADS * 8, 256, 0, stream>>>(
      adj, dist, mask, K, V, Wbuf, Kb, VTb);
  attn_kernel<<<BATCH * HEADS * (SEQ / 64), 256, 0, stream>>>(
      Q, Kb, VTb, mask, Wbuf, out, pattn);
}

// Round 4
// 529.080 us; speedup vs baseline: 1.1112x; 1.1112x over previous
//
#include <hip/hip_runtime.h>
#include <cmath>

// ---- problem constants ----
#define BATCH 16
#define HEADS 16
#define SEQ   512
#define DIM   64

#define LAMBDA_A 0.33f
#define LAMBDA_D 0.33f
#define LAMBDA_J 0.34f    // 1 - 0.33 - 0.33
#define NEG_BIG  1.0e12f

typedef float  floatx4 __attribute__((ext_vector_type(4)));
typedef short  shortx8 __attribute__((ext_vector_type(8)));
typedef short  shortx4 __attribute__((ext_vector_type(4)));

__device__ __forceinline__ unsigned short f2bf(float x){
  unsigned u = __builtin_bit_cast(unsigned, x);
  u += 0x7FFFu + ((u >> 16) & 1u);          // round-to-nearest-even
  return (unsigned short)(u >> 16);
}

// ---------------------------------------------------------------------------
// fused prep:
//   blocks [0, 2048):    W[b,q,k] = LAMBDA_D*p_dist + LAMBDA_J*adj_norm
//   blocks [2048, 4096): K -> bf16 (B,H,S,D), V -> bf16 V^T (B,H,D,S)
// ---------------------------------------------------------------------------
__global__ __launch_bounds__(256, 8) void prep_kernel(
    const float* __restrict__ adj, const float* __restrict__ dist,
    const float* __restrict__ mask, const float* __restrict__ K,
    const float* __restrict__ V, float* __restrict__ W,
    unsigned short* __restrict__ Kb, unsigned short* __restrict__ VTb)
{
  __shared__ unsigned short sT[64 * 72];
  int tid = threadIdx.x;

  if (blockIdx.x < BATCH * SEQ / 4){
    // ---- W prep: one wave per (b,q) row ----
    int lane = tid & 63;
    int row  = blockIdx.x * 4 + (tid >> 6);     // 0 .. B*SEQ-1
    int b = row >> 9, q = row & (SEQ - 1);
    const float* arow = adj  + ((size_t)b * SEQ + q) * SEQ;
    const float* drow = dist + ((size_t)b * SEQ + q) * SEQ;
    const float* mrow = mask + (size_t)b * SEQ;

    floatx4 a[2], e[2];
    float asum = 0.f, dsum = 0.f;
#pragma unroll
    for (int i = 0; i < 2; i++){
      int c4 = (i * 64 + lane) * 4;
      a[i] = *(const floatx4*)(arow + c4);
      floatx4 d4 = *(const floatx4*)(drow + c4);
      floatx4 m4 = *(const floatx4*)(mrow + c4);
#pragma unroll
      for (int j = 0; j < 4; j++){
        asum += a[i][j];
        float ex = (m4[j] == 0.f) ? 0.f : __expf(-d4[j]);
        e[i][j] = ex;
        dsum += ex;
      }
    }
#pragma unroll
    for (int off = 1; off < 64; off <<= 1){
      asum += __shfl_xor(asum, off);
      dsum += __shfl_xor(dsum, off);
    }
    float ia = LAMBDA_J / (asum + 1e-6f);
    float id = LAMBDA_D / dsum;

    float* wrow = W + ((size_t)b * SEQ + q) * SEQ;
#pragma unroll
    for (int i = 0; i < 2; i++){
      int c4 = (i * 64 + lane) * 4;
      floatx4 w;
#pragma unroll
      for (int j = 0; j < 4; j++) w[j] = e[i][j] * id + a[i][j] * ia;
      *(floatx4*)(wrow + c4) = w;
    }
    return;
  }

  // ---- K/V prep: one block per (bh, 64-row chunk) ----
  int bid = blockIdx.x - BATCH * SEQ / 4;
  int c   = bid & 7;
  int bh  = bid >> 3;
  const float* Kp = K + ((size_t)bh * SEQ + c * 64) * DIM;
  const float* Vp = V + ((size_t)bh * SEQ + c * 64) * DIM;
  unsigned short* Ko = Kb  + ((size_t)bh * SEQ + c * 64) * DIM;
  unsigned short* Vo = VTb + (size_t)bh * DIM * SEQ;

#pragma unroll
  for (int i = 0; i < 2; i++){
    int idx = (i * 256 + tid) * 8;
    floatx4 v0 = *(const floatx4*)(Kp + idx);
    floatx4 v1 = *(const floatx4*)(Kp + idx + 4);
    shortx8 hh;
#pragma unroll
    for (int j = 0; j < 4; j++){
      hh[j]     = (short)f2bf(v0[j]);
      hh[j + 4] = (short)f2bf(v1[j]);
    }
    *(shortx8*)(Ko + idx) = hh;
  }

#pragma unroll
  for (int i = 0; i < 4; i++){
    int idx = (i * 256 + tid) * 4;
    int k = idx >> 6, d = idx & 63;
    floatx4 v = *(const floatx4*)(Vp + idx);
#pragma unroll
    for (int j = 0; j < 4; j++) sT[(d + j) * 72 + k] = f2bf(v[j]);
  }
  __syncthreads();
#pragma unroll
  for (int i = 0; i < 2; i++){
    int idx = i * 256 + tid;
    int d = idx >> 3, k8 = idx & 7;
    shortx8 hh = *(const shortx8*)&sT[d * 72 + k8 * 8];
    *(shortx8*)(Vo + (size_t)d * SEQ + c * 64 + k8 * 8) = hh;
  }
}

// ---------------------------------------------------------------------------
// main kernel: block = (b, h, 32 q-rows); wave (mt,p) = q-rows [mt*16,+16)
// x contiguous key half [p*256,+256).  Scores in regs (acc[16] = 64 VGPR).
//  - QK^T swapped (A=K, B=Q): acc[j][r] = s[key=p*256+j*16+quad*4+r][q=l15]
//  - softmax: per-lane tree + shfl_xor(16,32) + tiny LDS cross-parity (1 barrier)
//  - PV: wave-private slab transpose (no barrier), partial over key half,
//        cross-parity sum via padded LDS (1 barrier).  2 barriers total.
//  - grid: bx = qt | h<<4 | b<<8 -> W-panel sharers (same b,qt; all h) land
//    on the same XCD (bx mod 8 == qt mod 8).
// ---------------------------------------------------------------------------
__global__ __launch_bounds__(256, 4) void attn_kernel(
    const float* __restrict__ Q, const unsigned short* __restrict__ Kb,
    const unsigned short* __restrict__ VTb, const float* __restrict__ mask,
    const float* __restrict__ W, float* __restrict__ out, float* __restrict__ pattn)
{
  int bx = blockIdx.x;
  int qt = bx & 15;
  int h  = (bx >> 4) & 15;
  int b  = bx >> 8;
  int bh = b * HEADS + h;
  int q0b = qt * 32;

  int tid  = threadIdx.x;
  int wv   = tid >> 6;
  int lane = tid & 63;
  int l15  = lane & 15;
  int quad = lane >> 4;
  int mt   = wv >> 1;          // q-row half of the 32-row tile
  int p    = wv & 1;           // key half

  __shared__ short   sPW[4][16 * 72];    // per-wave private slab
  __shared__ floatx4 sPart[2][64][5];    // padded PV partials (p=1 -> p=0)
  __shared__ float   sRedM[2][32];
  __shared__ float   sRedS[2][32];
  short* slab = &sPW[wv][0];

  // ---- Q fragments (B operand), rows q = q0b + mt*16 + l15, prescaled ----
  const float* Qp = Q + ((size_t)bh * SEQ + q0b + mt * 16 + l15) * DIM + quad * 8;
  shortx8 qf[2];
#pragma unroll
  for (int ks = 0; ks < 2; ks++){
    floatx4 v0 = *(const floatx4*)(Qp + ks * 32);
    floatx4 v1 = *(const floatx4*)(Qp + ks * 32 + 4);
#pragma unroll
    for (int j = 0; j < 4; j++){
      qf[ks][j]     = (short)f2bf(v0[j] * 0.125f);
      qf[ks][j + 4] = (short)f2bf(v1[j] * 0.125f);
    }
  }

  // ---- QK^T: 16 key-tiles of this wave's half, direct from L2 bf16 K ----
  const unsigned short* Kw = Kb + (size_t)bh * SEQ * DIM
                                + (size_t)(p * 256 + l15) * DIM + quad * 8;
  floatx4 acc[16];
#pragma unroll
  for (int j = 0; j < 16; j++) acc[j] = (floatx4)0.f;
#pragma unroll
  for (int j = 0; j < 16; j++){
    const unsigned short* Kt = Kw + (size_t)j * 16 * DIM;
    shortx8 k0 = *(const shortx8*)(Kt);
    shortx8 k1 = *(const shortx8*)(Kt + 32);
    acc[j] = __builtin_amdgcn_mfma_f32_16x16x32_bf16(k0, qf[0], acc[j], 0, 0, 0);
    acc[j] = __builtin_amdgcn_mfma_f32_16x16x32_bf16(k1, qf[1], acc[j], 0, 0, 0);
  }

  // ---- mask + wave-local max (4 independent chains, then tree) ----
  const float* mrow = mask + b * SEQ + p * 256 + quad * 4;
  float mx4[4] = {-INFINITY, -INFINITY, -INFINITY, -INFINITY};
#pragma unroll
  for (int j = 0; j < 16; j++){
    floatx4 m4 = *(const floatx4*)(mrow + j * 16);
#pragma unroll
    for (int r = 0; r < 4; r++){
      float s = (m4[r] == 0.f) ? -NEG_BIG : acc[j][r];
      acc[j][r] = s;
      mx4[r] = fmaxf(mx4[r], s);
    }
  }
  float mx = fmaxf(fmaxf(mx4[0], mx4[1]), fmaxf(mx4[2], mx4[3]));
  mx = fmaxf(mx, __shfl_xor(mx, 16));
  mx = fmaxf(mx, __shfl_xor(mx, 32));

  // ---- exp + wave-local sum ----
  float sm4[4] = {0.f, 0.f, 0.f, 0.f};
#pragma unroll
  for (int j = 0; j < 16; j++){
#pragma unroll
    for (int r = 0; r < 4; r++){
      float e = __expf(acc[j][r] - mx);
      acc[j][r] = e;
      sm4[r] += e;
    }
  }
  float sm = (sm4[0] + sm4[1]) + (sm4[2] + sm4[3]);
  sm += __shfl_xor(sm, 16);
  sm += __shfl_xor(sm, 32);

  // ---- cross-parity (m, l) combine: one barrier ----
  if (lane < 16){
    sRedM[p][mt * 16 + l15] = mx;
    sRedS[p][mt * 16 + l15] = sm;
  }
  __syncthreads();
  float m0 = sRedM[0][mt * 16 + l15], m1 = sRedM[1][mt * 16 + l15];
  float l0 = sRedS[0][mt * 16 + l15], l1 = sRedS[1][mt * 16 + l15];
  float mg = fmaxf(m0, m1);
  float lg = l0 * __expf(m0 - mg) + l1 * __expf(m1 - mg);
  float corr   = __expf(mx - mg);        // rescale this wave's e-values
  float inv_l  = corr / lg;              // e * inv_l = p_attn
  float lam_il = LAMBDA_A * inv_l;

  // ---- PV over this wave's key half: slab transpose, no barriers ----
  float* pAl = pattn + ((size_t)bh * SEQ + q0b + mt * 16 + l15) * SEQ
                     + p * 256 + quad * 4;
  const float* Wl = W + ((size_t)b * SEQ + q0b + mt * 16 + l15) * SEQ
                      + p * 256 + quad * 4;
  const unsigned short* Vw = VTb + (size_t)bh * DIM * SEQ
                                 + (size_t)l15 * SEQ + p * 256 + quad * 8;

  floatx4 acc2[4];
#pragma unroll
  for (int d = 0; d < 4; d++) acc2[d] = (floatx4)0.f;

#pragma unroll
  for (int cc = 0; cc < 4; cc++){
    // W for this chunk
    floatx4 wc[4];
#pragma unroll
    for (int jj = 0; jj < 4; jj++)
      wc[jj] = *(const floatx4*)(Wl + cc * 64 + jj * 16);

    // build: p_attn float4 store + bf16 p_weighted into slab
#pragma unroll
    for (int jj = 0; jj < 4; jj++){
      int j = cc * 4 + jj;
      floatx4 pa;
      shortx4 pw;
#pragma unroll
      for (int r = 0; r < 4; r++){
        float e = acc[j][r];
        pa[r] = e * inv_l;
        pw[r] = (short)f2bf(fmaf(e, lam_il, wc[jj][r]));
      }
      __builtin_nontemporal_store(pa, (floatx4*)(pAl + j * 16));
      *(shortx4*)&slab[l15 * 72 + jj * 16 + quad * 4] = pw;
    }

    // PV MFMA (A from slab, B streams from V^T)
    const unsigned short* Vc = Vw + cc * 64;
#pragma unroll
    for (int ks = 0; ks < 2; ks++){
      shortx8 a2 = *(const shortx8*)&slab[l15 * 72 + ks * 32 + quad * 8];
#pragma unroll
      for (int d = 0; d < 4; d++){
        shortx8 vf = *(const shortx8*)(Vc + (size_t)d * 16 * SEQ + ks * 32);
        acc2[d] = __builtin_amdgcn_mfma_f32_16x16x32_bf16(a2, vf, acc2[d], 0, 0, 0);
      }
    }
  }

  // ---- cross-parity partial sum: one barrier ----
  if (p == 1){
#pragma unroll
    for (int d = 0; d < 4; d++) sPart[mt][lane][d] = acc2[d];
  }
  __syncthreads();
  if (p == 0){
    float* ob = out + ((size_t)bh * SEQ + q0b + mt * 16 + quad * 4) * DIM + l15;
#pragma unroll
    for (int d = 0; d < 4; d++){
      floatx4 o = acc2[d] + sPart[mt][lane][d];
#pragma unroll
      for (int r = 0; r < 4; r++)
        __builtin_nontemporal_store(o[r], ob + (size_t)r * DIM + d * 16);
    }
  }
}

extern "C" void kernel_launch(void* const* d_in, const int* in_sizes, int n_in,
                              void* d_out, int out_size, void* d_ws, size_t ws_size,
                              hipStream_t stream){
  const float* Q    = (const float*)d_in[0];
  const float* K    = (const float*)d_in[1];
  const float* V    = (const float*)d_in[2];
  const float* mask = (const float*)d_in[3];
  const float* adj  = (const float*)d_in[4];
  const float* dist = (const float*)d_in[5];
  float* out   = (float*)d_out;
  float* pattn = out + (size_t)BATCH * HEADS * SEQ * DIM;   // 8,388,608

  // workspace layout (48 MiB):
  //   [0,16M)   W     f32  (B,S,S)   head-independent weight term
  //   [16M,32M) Kb    bf16 (B,H,S,D)
  //   [32M,48M) VT    bf16 (B,H,D,S)
  float*          Wbuf = (float*)d_ws;
  unsigned short* Kb   = (unsigned short*)((char*)d_ws + (size_t)16 * 1024 * 1024);
  unsigned short* VTb  = (unsigned short*)((char*)d_ws + (size_t)32 * 1024 * 1024);

  prep_kernel<<<BATCH * SEQ / 4 + BATCH * HEADS * 8, 256, 0, stream>>>(
      adj, dist, mask, K, V, Wbuf, Kb, VTb);
  attn_kernel<<<BATCH * HEADS * (SEQ / 32), 256, 0, stream>>>(
      Q, Kb, VTb, mask, Wbuf, out, pattn);
}